// Round 13
// baseline (212.231 us; speedup 1.0000x reference)
//
#include <hip/hip_runtime.h>
#include <hip/hip_bf16.h>
#include <math.h>

#define S 2048
#define CDIM 1024
#define H 256
#define HS 2048
#define E 16
#define GNUM 4
#define EPG 4
#define TOPK 4
#define KSLICES 8

typedef __attribute__((ext_vector_type(8))) short bfrag_t;   // 8 bf16 = 4 VGPRs
typedef __attribute__((ext_vector_type(4))) float facc_t;    // 4 fp32 acc
typedef __attribute__((ext_vector_type(4))) unsigned int u32x4;
typedef __attribute__((ext_vector_type(4))) unsigned short u16x4;

__device__ __forceinline__ float sigmoidf_(float v) { return 1.f / (1.f + __expf(-v)); }

__device__ __forceinline__ unsigned short f2bf(float f) {
    union { float f; unsigned u; } v; v.f = f;
    unsigned r = v.u + 0x7FFFu + ((v.u >> 16) & 1u);   // round-to-nearest-even
    return (unsigned short)(r >> 16);
}
__device__ __forceinline__ float bf2f(unsigned short u) {
    union { unsigned u; float f; } v; v.u = ((unsigned)u) << 16; return v.f;
}
__device__ __forceinline__ unsigned long long pack4(float4 v) {
    return (unsigned long long)f2bf(v.x)
         | ((unsigned long long)f2bf(v.y) << 16)
         | ((unsigned long long)f2bf(v.z) << 32)
         | ((unsigned long long)f2bf(v.w) << 48);
}

// 16B/lane global->LDS DMA. LDS base is wave-uniform; lane L lands at l + L*16B.
__device__ __forceinline__ void stage16(const unsigned short* g, unsigned short* l, int lane) {
#if __has_builtin(__builtin_amdgcn_global_load_lds)
    __builtin_amdgcn_global_load_lds(
        (const __attribute__((address_space(1))) void*)g,
        (__attribute__((address_space(3))) void*)l, 16, 0, 0);
#else
    *(u32x4*)(l + lane * 8) = *(const u32x4*)g;
#endif
}

struct CastArgs {
    const float4* src[3];
    unsigned long long* dst[3];
};

// ---------------------------------------------------------------------------
// PREPROC mega-kernel. Round-13: logits slab stride 129 -> 132 (rows 16B
// aligned) so the dot-product + cast re-read use float4 LDS loads (4x fewer
// LDS instructions; 2-way bank alias = free). Semantics identical.
// ---------------------------------------------------------------------------
#define LG_BLOCKS   ((S / 16) * KSLICES)                    // 1024
#define CAST_BLOCKS (3 * (HS * CDIM / 16 / 256))            // 1536
#define TGU_BLOCKS  (2 * E * (CDIM / 64) * (H / 64))        // 2048
#define TDN_BLOCKS  (E * (H / 64) * (CDIM / 64))            // 1024

__global__ __launch_bounds__(256) void preproc_kernel(
    const float* __restrict__ x, const float* __restrict__ rw,
    float* __restrict__ lgpart, unsigned short* __restrict__ xb,
    CastArgs ca,
    const float* __restrict__ gate_w, unsigned short* __restrict__ gwT,
    const float* __restrict__ up_w,  unsigned short* __restrict__ uwT,
    const float* __restrict__ down_w, unsigned short* __restrict__ dwT)
{
    __shared__ __align__(16) float sbuf[64 * 66];   // 16896 B, shared by partitions
    const int tid = threadIdx.x;
    int id = blockIdx.x;

    if (id < LG_BLOCKS) {
        // ---- logits + x cast, LDS-staged, coalesced, float4 LDS reads ----
        const int ks = id >> 7;
        const int s0 = (id & 127) * 16;
        float* xs  = sbuf;              // [16][132] x-slab (stride 132: 16B-aligned rows)
        float* wsl = sbuf + 16 * 132;   // [16][132] rw-slab (total 16896 B)
#pragma unroll
        for (int r = 0; r < 2; ++r) {
            int idx = r * 256 + tid;          // 0..511
            int row = idx >> 5;               // 0..15
            int c4  = (idx & 31) * 4;         // 0..124
            float4 xv = *(const float4*)&x[(size_t)(s0 + row) * CDIM + ks * (CDIM / KSLICES) + c4];
            float4 wv = *(const float4*)&rw[(size_t)row * CDIM + ks * (CDIM / KSLICES) + c4];
            *(float4*)&xs[row * 132 + c4] = xv;    // 16B-aligned (132*4 % 16 == 0)
            *(float4*)&wsl[row * 132 + c4] = wv;
        }
        __syncthreads();
        const int t = tid & 15, e = tid >> 4;
        const float4* xr = (const float4*)&xs[t * 132];
        const float4* wr = (const float4*)&wsl[e * 132];
        float acc = 0.f;
#pragma unroll 8
        for (int c = 0; c < CDIM / KSLICES / 4; ++c) {
            float4 a = xr[c], b = wr[c];
            acc += a.x * b.x + a.y * b.y + a.z * b.z + a.w * b.w;
        }
        lgpart[((size_t)ks * S + s0 + t) * E + e] = acc;
        // coalesced cast: wave writes 4 x 256B contiguous segments
        const int tok = tid >> 4, off = (tid & 15) * 8;
        const float4* pr = (const float4*)&xs[tok * 132 + off];
        float4 v0 = pr[0], v1 = pr[1];
        unsigned long long* dst = (unsigned long long*)
            (xb + (size_t)(s0 + tok) * CDIM + ks * (CDIM / KSLICES) + off);
        dst[0] = pack4(v0);
        dst[1] = pack4(v1);
        return;
    }
    id -= LG_BLOCKS;

    if (id < CAST_BLOCKS) {
        // ---- shared-weight casts: 512 blocks per buffer, 4 float4/thread ----
        const int buf = id >> 9;
        const int i0 = (id & 511) * 1024 + tid;
        const float4* src = ca.src[buf];
        unsigned long long* dst = ca.dst[buf];
#pragma unroll
        for (int j = 0; j < 4; ++j)
            dst[i0 + j * 256] = pack4(src[i0 + j * 256]);
        return;
    }
    id -= CAST_BLOCKS;

    // ---- 64x64 vectorized transposes (round-5 version, tbuf stride 65) ----
    float* tbuf = sbuf;   // [64][65] uses 16640 of 16896 B
    const float* src; unsigned short* dst; int R, Cc, zz, c0, r0;
    if (id < TGU_BLOCKS) {
        const int bx = id & 3; const int by = (id >> 2) & 15; const int bz = id >> 6;
        R = CDIM; Cc = H;
        src = (bz < E) ? gate_w : up_w;
        dst = (bz < E) ? gwT : uwT;
        zz = (bz < E) ? bz : bz - E;
        c0 = bx * 64; r0 = by * 64;
    } else {
        id -= TGU_BLOCKS;
        const int bx = id & 15; const int by = (id >> 4) & 3; const int bz = id >> 6;
        R = H; Cc = CDIM;
        src = down_w; dst = dwT; zz = bz;
        c0 = bx * 64; r0 = by * 64;
    }
    const size_t mo = (size_t)zz * R * Cc;
    src += mo; dst += mo;
    const int tx = tid & 15, ty = tid >> 4;   // 16 x 16
#pragma unroll
    for (int i = 0; i < 4; ++i) {
        const int row = ty + 16 * i;
        float4 v = *(const float4*)&src[(size_t)(r0 + row) * Cc + c0 + tx * 4];
        float* p = &tbuf[row * 65 + tx * 4];
        p[0] = v.x; p[1] = v.y; p[2] = v.z; p[3] = v.w;
    }
    __syncthreads();
#pragma unroll
    for (int j = 0; j < 4; ++j) {
        const int c = ty + 16 * j;
        u16x4 o;
#pragma unroll
        for (int i = 0; i < 4; ++i)
            o[i] = f2bf(tbuf[(tx * 4 + i) * 65 + c]);
        *(u16x4*)&dst[(size_t)(c0 + c) * R + r0 + tx * 4] = o;
    }
}

// ---------------------------------------------------------------------------
// K1b: route (hierarchical compaction, unchanged).
// ---------------------------------------------------------------------------
__global__ __launch_bounds__(256) void route_kernel(
    const float* __restrict__ lgpart, const float* __restrict__ bias,
    int* __restrict__ counts, int* __restrict__ list, float* __restrict__ wlist)
{
    __shared__ int lcount[E];
    __shared__ int lbase[E];
    const int tid = threadIdx.x;
    const int s = blockIdx.x * 256 + tid;
    if (tid < E) lcount[tid] = 0;
    float lgv[E];
#pragma unroll
    for (int i = 0; i < E; ++i) lgv[i] = 0.f;
#pragma unroll
    for (int ks = 0; ks < KSLICES; ++ks) {
        const float4* p = (const float4*)(lgpart + ((size_t)ks * S + s) * E);
#pragma unroll
        for (int q = 0; q < 4; ++q) {
            float4 v = p[q];
            lgv[q * 4 + 0] += v.x; lgv[q * 4 + 1] += v.y;
            lgv[q * 4 + 2] += v.z; lgv[q * 4 + 3] += v.w;
        }
    }
    float sc[E], sb[E];
#pragma unroll
    for (int e2 = 0; e2 < E; ++e2) {
        sc[e2] = 1.f / (1.f + __expf(-lgv[e2]));
        sb[e2] = sc[e2] + bias[e2];
    }
    float gsc[GNUM];
#pragma unroll
    for (int g = 0; g < GNUM; ++g) {
        int b_ = g * EPG;
        int m1 = 0; float v1 = sb[b_];
#pragma unroll
        for (int j = 1; j < EPG; ++j) if (sb[b_ + j] > v1) { v1 = sb[b_ + j]; m1 = j; }
        float v2 = -1e30f;
#pragma unroll
        for (int j = 0; j < EPG; ++j) if (j != m1 && sb[b_ + j] > v2) v2 = sb[b_ + j];
        gsc[g] = v1 + v2;
    }
    int g1 = 0;
#pragma unroll
    for (int g = 1; g < GNUM; ++g) if (gsc[g] > gsc[g1]) g1 = g;
    int g2 = (g1 == 0) ? 1 : 0;
#pragma unroll
    for (int g = 0; g < GNUM; ++g) if (g != g1 && gsc[g] > gsc[g2]) g2 = g;
    bool allowed[E];
#pragma unroll
    for (int e2 = 0; e2 < E; ++e2) {
        int g = e2 >> 2;
        allowed[e2] = (g == g1) || (g == g2);
    }
    int idx[TOPK]; float wk[TOPK];
#pragma unroll
    for (int k = 0; k < TOPK; ++k) {
        int best = 0; float bv = -1e30f;
#pragma unroll
        for (int e2 = 0; e2 < E; ++e2)
            if (allowed[e2] && sb[e2] > bv) { bv = sb[e2]; best = e2; }
        allowed[best] = false;
        idx[k] = best;
        wk[k] = sc[best];
    }
    float inv = 1.f / (wk[0] + wk[1] + wk[2] + wk[3] + 1e-20f);
    __syncthreads();
    int lpos[TOPK];
#pragma unroll
    for (int k = 0; k < TOPK; ++k)
        lpos[k] = atomicAdd(&lcount[idx[k]], 1);
    __syncthreads();
    if (tid < E)
        lbase[tid] = atomicAdd(&counts[tid], lcount[tid]);
    __syncthreads();
#pragma unroll
    for (int k = 0; k < TOPK; ++k) {
        int ee = idx[k];
        int pos = lbase[ee] + lpos[k];
        list[ee * S + pos] = s | (k << 16);
        wlist[ee * S + pos] = wk[k] * inv;
    }
}

// ---------------------------------------------------------------------------
// m97-style MFMA GEMMs, BK=64 single-buffer. K4 @ BM=128 (512 blocks),
// K5/K6 @ 64x64 (proven), K7 now @ BM=128 (active blocks 1024 = 4/CU,
// 2x MFMA-per-barrier; body correctness-proven in round 6).
// ---------------------------------------------------------------------------

// K4: shared gate+up fused SwiGLU -> shb bf16 [S][HS]. BM=128/BN=64, BK=64.
// grid (HS/64=32, S/128=16).
__global__ __launch_bounds__(256) void gemm_shared_gateup(
    const unsigned short* __restrict__ xb, const unsigned short* __restrict__ gb,
    const unsigned short* __restrict__ ub, unsigned short* __restrict__ shb)
{
    __shared__ __align__(16) unsigned short As[2 * 128 * 32];
    __shared__ __align__(16) unsigned short Bg[2 * 64 * 32];
    __shared__ __align__(16) unsigned short Bu[2 * 64 * 32];
    const int tid = threadIdx.x;
    const int lane = tid & 63, w = tid >> 6;
    const int l15 = lane & 15, q = lane >> 4;
    const int r0 = blockIdx.y * 128;
    const int c0 = blockIdx.x * 64;
    const int wr = (w >> 1) * 64, wc = (w & 1) * 32;
    const int Lrow = lane >> 2;
    const int gseg = (lane & 3) ^ ((lane >> 3) & 3);
    const unsigned short* gA1 = xb + (size_t)(r0 + w * 16 + Lrow) * CDIM + gseg * 8;
    const unsigned short* gA2 = gA1 + (size_t)64 * CDIM;
    const unsigned short* gG  = gb + (size_t)(c0 + w * 16 + Lrow) * CDIM + gseg * 8;
    const unsigned short* gU  = ub + (size_t)(c0 + w * 16 + Lrow) * CDIM + gseg * 8;
    unsigned short* lA1 = &As[(w * 16) * 32];
    unsigned short* lA2 = lA1 + 64 * 32;
    unsigned short* lG  = &Bg[(w * 16) * 32];
    unsigned short* lU  = &Bu[(w * 16) * 32];
    const int swq = (q ^ ((l15 >> 1) & 3)) * 8;
    facc_t accg[4][2], accu[4][2];
#pragma unroll
    for (int i = 0; i < 4; ++i)
#pragma unroll
        for (int j = 0; j < 2; ++j) { accg[i][j] = 0.f; accu[i][j] = 0.f; }
    for (int k0 = 0; k0 < CDIM; k0 += 64) {
        stage16(gA1 + k0,      lA1,             lane);
        stage16(gA1 + k0 + 32, lA1 + 128 * 32,  lane);
        stage16(gA2 + k0,      lA2,             lane);
        stage16(gA2 + k0 + 32, lA2 + 128 * 32,  lane);
        stage16(gG + k0,       lG,              lane);
        stage16(gG + k0 + 32,  lG + 64 * 32,    lane);
        stage16(gU + k0,       lU,              lane);
        stage16(gU + k0 + 32,  lU + 64 * 32,    lane);
        __syncthreads();
#pragma unroll
        for (int kk = 0; kk < 2; ++kk) {
            const unsigned short* Ah = &As[kk * 128 * 32];
            const unsigned short* Gh = &Bg[kk * 64 * 32];
            const unsigned short* Uh = &Bu[kk * 64 * 32];
            bfrag_t af[4], gf[2], uf[2];
#pragma unroll
            for (int i = 0; i < 4; ++i)
                af[i] = *(const bfrag_t*)&Ah[(wr + i * 16 + l15) * 32 + swq];
#pragma unroll
            for (int j = 0; j < 2; ++j) {
                gf[j] = *(const bfrag_t*)&Gh[(wc + j * 16 + l15) * 32 + swq];
                uf[j] = *(const bfrag_t*)&Uh[(wc + j * 16 + l15) * 32 + swq];
            }
#pragma unroll
            for (int i = 0; i < 4; ++i)
#pragma unroll
                for (int j = 0; j < 2; ++j) {
                    accg[i][j] = __builtin_amdgcn_mfma_f32_16x16x32_bf16(af[i], gf[j], accg[i][j], 0, 0, 0);
                    accu[i][j] = __builtin_amdgcn_mfma_f32_16x16x32_bf16(af[i], uf[j], accu[i][j], 0, 0, 0);
                }
        }
        __syncthreads();
    }
#pragma unroll
    for (int i = 0; i < 4; ++i)
#pragma unroll
        for (int j = 0; j < 2; ++j)
#pragma unroll
            for (int r = 0; r < 4; ++r) {
                int row = r0 + wr + i * 16 + q * 4 + r;
                int col = c0 + wc + j * 16 + l15;
                float g = accg[i][j][r], u = accu[i][j][r];
                shb[(size_t)row * HS + col] = f2bf(g * sigmoidf_(g) * u);
            }
}

// K5: shared down-proj + routed-sum epilogue -> out fp32 [S][CDIM].
// BM=64/BN=64, BK=64, K=HS. grid (CDIM/64=16, S/64=32). RUNS LAST.
__global__ __launch_bounds__(256) void gemm_shared_down(
    const unsigned short* __restrict__ shb, const unsigned short* __restrict__ db,
    const unsigned short* __restrict__ dbuf, float* __restrict__ out)
{
    __shared__ __align__(16) unsigned short As[2 * 64 * 32];
    __shared__ __align__(16) unsigned short Bs[2 * 64 * 32];
    const int tid = threadIdx.x;
    const int lane = tid & 63, w = tid >> 6;
    const int l15 = lane & 15, q = lane >> 4;
    const int r0 = blockIdx.y * 64;
    const int c0 = blockIdx.x * 64;
    const int wr = (w >> 1) * 32, wc = (w & 1) * 32;
    const int Lrow = lane >> 2;
    const int gseg = (lane & 3) ^ ((lane >> 3) & 3);
    const unsigned short* gA = shb + (size_t)(r0 + w * 16 + Lrow) * HS + gseg * 8;
    const unsigned short* gB = db + (size_t)(c0 + w * 16 + Lrow) * HS + gseg * 8;
    unsigned short* lA = &As[(w * 16) * 32];
    unsigned short* lB = &Bs[(w * 16) * 32];
    const int swq = (q ^ ((l15 >> 1) & 3)) * 8;
    facc_t acc[2][2];
#pragma unroll
    for (int i = 0; i < 2; ++i)
#pragma unroll
        for (int j = 0; j < 2; ++j) acc[i][j] = 0.f;
    for (int k0 = 0; k0 < HS; k0 += 64) {
        stage16(gA + k0,      lA,            lane);
        stage16(gA + k0 + 32, lA + 64 * 32,  lane);
        stage16(gB + k0,      lB,            lane);
        stage16(gB + k0 + 32, lB + 64 * 32,  lane);
        __syncthreads();
#pragma unroll
        for (int kk = 0; kk < 2; ++kk) {
            const unsigned short* Ah = &As[kk * 64 * 32];
            const unsigned short* Bh = &Bs[kk * 64 * 32];
            bfrag_t af[2], bf[2];
#pragma unroll
            for (int i = 0; i < 2; ++i) af[i] = *(const bfrag_t*)&Ah[(wr + i * 16 + l15) * 32 + swq];
#pragma unroll
            for (int j = 0; j < 2; ++j) bf[j] = *(const bfrag_t*)&Bh[(wc + j * 16 + l15) * 32 + swq];
#pragma unroll
            for (int i = 0; i < 2; ++i)
#pragma unroll
                for (int j = 0; j < 2; ++j)
                    acc[i][j] = __builtin_amdgcn_mfma_f32_16x16x32_bf16(af[i], bf[j], acc[i][j], 0, 0, 0);
        }
        __syncthreads();
    }
#pragma unroll
    for (int i = 0; i < 2; ++i)
#pragma unroll
        for (int j = 0; j < 2; ++j)
#pragma unroll
            for (int r = 0; r < 4; ++r) {
                int row = r0 + wr + i * 16 + q * 4 + r;
                int col = c0 + wc + j * 16 + l15;
                float v = acc[i][j][r];
                const unsigned short* dp = dbuf + ((size_t)row * TOPK) * CDIM + col;
#pragma unroll
                for (int k = 0; k < TOPK; ++k) v += bf2f(dp[(size_t)k * CDIM]);
                out[(size_t)row * CDIM + col] = v;
            }
}

// K6: routed gate+up, gathered A rows, weighted SwiGLU -> hbuf bf16 [S*4][H].
// BM=64/BN=64, BK=64. grid (E, H/64=4, S/64=32).
__global__ __launch_bounds__(256) void gemm_routed_gateup(
    const unsigned short* __restrict__ xb, const unsigned short* __restrict__ gwT,
    const unsigned short* __restrict__ uwT, const int* __restrict__ counts,
    const int* __restrict__ list, const float* __restrict__ wlist,
    unsigned short* __restrict__ hbuf)
{
    const int e = blockIdx.x;
    const int n = counts[e];
    const int t0 = blockIdx.z * 64;
    if (t0 >= n) return;
    const int h0 = blockIdx.y * 64;
    __shared__ int toks[64];
    __shared__ int hrw[64];
    __shared__ float wv[64];
    __shared__ __align__(16) unsigned short As[2 * 64 * 32];
    __shared__ __align__(16) unsigned short Bg[2 * 64 * 32];
    __shared__ __align__(16) unsigned short Bu[2 * 64 * 32];
    const int tid = threadIdx.x;
    if (tid < 64) {
        int p = t0 + tid;
        if (p < n) {
            int pk = list[e * S + p];
            toks[tid] = pk & 0xFFFF;
            hrw[tid] = (pk & 0xFFFF) * TOPK + (pk >> 16);
            wv[tid] = wlist[e * S + p];
        } else { toks[tid] = 0; hrw[tid] = 0; wv[tid] = 0.f; }
    }
    __syncthreads();
    const int lane = tid & 63, w = tid >> 6;
    const int l15 = lane & 15, q = lane >> 4;
    const int wr = (w >> 1) * 32, wc = (w & 1) * 32;
    const int Lrow = lane >> 2;
    const int gseg = (lane & 3) ^ ((lane >> 3) & 3);
    const int tokA = toks[w * 16 + Lrow];        // per-lane gathered A row
    const unsigned short* gA = xb + (size_t)tokA * CDIM + gseg * 8;
    const unsigned short* gG = gwT + ((size_t)e * H + h0 + w * 16 + Lrow) * CDIM + gseg * 8;
    const unsigned short* gU = uwT + ((size_t)e * H + h0 + w * 16 + Lrow) * CDIM + gseg * 8;
    unsigned short* lA = &As[(w * 16) * 32];
    unsigned short* lG = &Bg[(w * 16) * 32];
    unsigned short* lU = &Bu[(w * 16) * 32];
    const int swq = (q ^ ((l15 >> 1) & 3)) * 8;
    facc_t accg[2][2], accu[2][2];
#pragma unroll
    for (int i = 0; i < 2; ++i)
#pragma unroll
        for (int j = 0; j < 2; ++j) { accg[i][j] = 0.f; accu[i][j] = 0.f; }
    for (int k0 = 0; k0 < CDIM; k0 += 64) {
        stage16(gA + k0,      lA,            lane);
        stage16(gA + k0 + 32, lA + 64 * 32,  lane);
        stage16(gG + k0,      lG,            lane);
        stage16(gG + k0 + 32, lG + 64 * 32,  lane);
        stage16(gU + k0,      lU,            lane);
        stage16(gU + k0 + 32, lU + 64 * 32,  lane);
        __syncthreads();
#pragma unroll
        for (int kk = 0; kk < 2; ++kk) {
            const unsigned short* Ah = &As[kk * 64 * 32];
            const unsigned short* Gh = &Bg[kk * 64 * 32];
            const unsigned short* Uh = &Bu[kk * 64 * 32];
            bfrag_t af[2], gf[2], uf[2];
#pragma unroll
            for (int i = 0; i < 2; ++i) af[i] = *(const bfrag_t*)&Ah[(wr + i * 16 + l15) * 32 + swq];
#pragma unroll
            for (int j = 0; j < 2; ++j) {
                gf[j] = *(const bfrag_t*)&Gh[(wc + j * 16 + l15) * 32 + swq];
                uf[j] = *(const bfrag_t*)&Uh[(wc + j * 16 + l15) * 32 + swq];
            }
#pragma unroll
            for (int i = 0; i < 2; ++i)
#pragma unroll
                for (int j = 0; j < 2; ++j) {
                    accg[i][j] = __builtin_amdgcn_mfma_f32_16x16x32_bf16(af[i], gf[j], accg[i][j], 0, 0, 0);
                    accu[i][j] = __builtin_amdgcn_mfma_f32_16x16x32_bf16(af[i], uf[j], accu[i][j], 0, 0, 0);
                }
        }
        __syncthreads();
    }
#pragma unroll
    for (int i = 0; i < 2; ++i)
#pragma unroll
        for (int j = 0; j < 2; ++j)
#pragma unroll
            for (int r = 0; r < 4; ++r) {
                int li = wr + i * 16 + q * 4 + r;
                if (t0 + li < n) {
                    int col = h0 + wc + j * 16 + l15;
                    float g = accg[i][j][r], u = accu[i][j][r];
                    hbuf[(size_t)hrw[li] * H + col] = f2bf(wv[li] * g * sigmoidf_(g) * u);
                }
            }
}

// K7: routed down-proj -> dbuf bf16 [S*4][CDIM]. BM=128/BN=64, BK=64, K=H=256.
// grid (E, CDIM/64=16, S/128=16); ~1024 active blocks = 4/CU.
// (BM=128 body correctness-proven in round 6.)
__global__ __launch_bounds__(256) void gemm_routed_down(
    const unsigned short* __restrict__ hbuf, const unsigned short* __restrict__ dwT,
    const int* __restrict__ counts, const int* __restrict__ list,
    unsigned short* __restrict__ dbuf)
{
    const int e = blockIdx.x;
    const int n = counts[e];
    const int t0 = blockIdx.z * 128;
    if (t0 >= n) return;
    const int c0 = blockIdx.y * 64;
    __shared__ int hrw[128];
    __shared__ __align__(16) unsigned short As[2 * 128 * 32];
    __shared__ __align__(16) unsigned short Bs[2 * 64 * 32];
    const int tid = threadIdx.x;
    if (tid < 128) {
        int p = t0 + tid;
        int pk = (p < n) ? list[e * S + p] : 0;
        hrw[tid] = (pk & 0xFFFF) * TOPK + (pk >> 16);
    }
    __syncthreads();
    const int lane = tid & 63, w = tid >> 6;
    const int l15 = lane & 15, q = lane >> 4;
    const int wr = (w >> 1) * 64, wc = (w & 1) * 32;
    const int Lrow = lane >> 2;
    const int gseg = (lane & 3) ^ ((lane >> 3) & 3);
    const unsigned short* gA1 = hbuf + (size_t)hrw[w * 16 + Lrow] * H + gseg * 8;
    const unsigned short* gA2 = hbuf + (size_t)hrw[64 + w * 16 + Lrow] * H + gseg * 8;
    const unsigned short* gB = dwT + ((size_t)e * CDIM + c0 + w * 16 + Lrow) * H + gseg * 8;
    unsigned short* lA1 = &As[(w * 16) * 32];
    unsigned short* lA2 = lA1 + 64 * 32;
    unsigned short* lB = &Bs[(w * 16) * 32];
    const int swq = (q ^ ((l15 >> 1) & 3)) * 8;
    facc_t acc[4][2];
#pragma unroll
    for (int i = 0; i < 4; ++i)
#pragma unroll
        for (int j = 0; j < 2; ++j) acc[i][j] = 0.f;
    for (int k0 = 0; k0 < H; k0 += 64) {
        stage16(gA1 + k0,      lA1,            lane);
        stage16(gA1 + k0 + 32, lA1 + 128 * 32, lane);
        stage16(gA2 + k0,      lA2,            lane);
        stage16(gA2 + k0 + 32, lA2 + 128 * 32, lane);
        stage16(gB + k0,       lB,             lane);
        stage16(gB + k0 + 32,  lB + 64 * 32,   lane);
        __syncthreads();
#pragma unroll
        for (int kk = 0; kk < 2; ++kk) {
            const unsigned short* Ah = &As[kk * 128 * 32];
            const unsigned short* Bh = &Bs[kk * 64 * 32];
            bfrag_t af[4], bf[2];
#pragma unroll
            for (int i = 0; i < 4; ++i) af[i] = *(const bfrag_t*)&Ah[(wr + i * 16 + l15) * 32 + swq];
#pragma unroll
            for (int j = 0; j < 2; ++j) bf[j] = *(const bfrag_t*)&Bh[(wc + j * 16 + l15) * 32 + swq];
#pragma unroll
            for (int i = 0; i < 4; ++i)
#pragma unroll
                for (int j = 0; j < 2; ++j)
                    acc[i][j] = __builtin_amdgcn_mfma_f32_16x16x32_bf16(af[i], bf[j], acc[i][j], 0, 0, 0);
        }
        __syncthreads();
    }
#pragma unroll
    for (int i = 0; i < 4; ++i)
#pragma unroll
        for (int j = 0; j < 2; ++j)
#pragma unroll
            for (int r = 0; r < 4; ++r) {
                int li = wr + i * 16 + q * 4 + r;
                if (t0 + li < n) {
                    int col = c0 + wc + j * 16 + l15;
                    dbuf[(size_t)hrw[li] * CDIM + col] = f2bf(acc[i][j][r]);
                }
            }
}

// ---------------------------------------------------------------------------
extern "C" void kernel_launch(void* const* d_in, const int* in_sizes, int n_in,
                              void* d_out, int out_size, void* d_ws, size_t ws_size,
                              hipStream_t stream)
{
    const float* x        = (const float*)d_in[0];
    const float* router_w = (const float*)d_in[1];
    const float* bias     = (const float*)d_in[2];
    const float* gate_w   = (const float*)d_in[3];
    const float* up_w     = (const float*)d_in[4];
    const float* down_w   = (const float*)d_in[5];
    const float* sgw      = (const float*)d_in[6];
    const float* suw      = (const float*)d_in[7];
    const float* sdw      = (const float*)d_in[8];
    float* out = (float*)d_out;

    char* ws = (char*)d_ws;
    size_t off = 0;
    int* counts = (int*)(ws + off);            off += 256;
    int* list   = (int*)(ws + off);            off += (size_t)E * S * 4;
    float* wlist = (float*)(ws + off);         off += (size_t)E * S * 4;
    unsigned short* xb  = (unsigned short*)(ws + off); off += (size_t)S * CDIM * 2;
    unsigned short* sgb = (unsigned short*)(ws + off); off += (size_t)HS * CDIM * 2;
    unsigned short* sub = (unsigned short*)(ws + off); off += (size_t)HS * CDIM * 2;
    unsigned short* sdb = (unsigned short*)(ws + off); off += (size_t)CDIM * HS * 2;
    unsigned short* gwT = (unsigned short*)(ws + off); off += (size_t)E * H * CDIM * 2;
    unsigned short* uwT = (unsigned short*)(ws + off); off += (size_t)E * H * CDIM * 2;
    unsigned short* dwT = (unsigned short*)(ws + off); off += (size_t)E * CDIM * H * 2;
    unsigned short* shb = (unsigned short*)(ws + off); off += (size_t)S * HS * 2;
    unsigned short* hbuf = (unsigned short*)(ws + off); off += (size_t)S * TOPK * H * 2;
    unsigned short* dbuf = (unsigned short*)(ws + off); off += (size_t)S * TOPK * CDIM * 2;
    // lgpart (8*S*E floats = 1 MiB) aliases dbuf (consumed by route_kernel
    // before gemm_routed_down writes dbuf; same stream, serial).
    float* lgpart = (float*)dbuf;

    hipMemsetAsync(counts, 0, E * sizeof(int), stream);

    CastArgs ca;
    ca.src[0] = (const float4*)sgw; ca.dst[0] = (unsigned long long*)sgb;
    ca.src[1] = (const float4*)suw; ca.dst[1] = (unsigned long long*)sub;
    ca.src[2] = (const float4*)sdw; ca.dst[2] = (unsigned long long*)sdb;

    preproc_kernel<<<LG_BLOCKS + CAST_BLOCKS + TGU_BLOCKS + TDN_BLOCKS, 256, 0, stream>>>(
        x, router_w, lgpart, xb, ca, gate_w, gwT, up_w, uwT, down_w, dwT);

    route_kernel<<<S / 256, 256, 0, stream>>>(lgpart, bias, counts, list, wlist);

    gemm_shared_gateup<<<dim3(HS / 64, S / 128), 256, 0, stream>>>(xb, sgb, sub, shb);
    gemm_routed_gateup<<<dim3(E, H / 64, S / 64), 256, 0, stream>>>(xb, gwT, uwT, counts, list, wlist, hbuf);
    gemm_routed_down<<<dim3(E, CDIM / 64, S / 128), 256, 0, stream>>>(hbuf, dwT, counts, list, dbuf);
    // LAST: shared down-proj with fused routed-sum epilogue (reads dbuf).
    gemm_shared_down<<<dim3(CDIM / 64, S / 64), 256, 0, stream>>>(shb, sdb, dbuf, out);
}

// Round 14
// 209.181 us; speedup vs baseline: 1.0146x; 1.0146x over previous
//
#include <hip/hip_runtime.h>
#include <hip/hip_bf16.h>
#include <math.h>

#define S 2048
#define CDIM 1024
#define H 256
#define HS 2048
#define E 16
#define GNUM 4
#define EPG 4
#define TOPK 4
#define KSLICES 8

typedef __attribute__((ext_vector_type(8))) short bfrag_t;   // 8 bf16 = 4 VGPRs
typedef __attribute__((ext_vector_type(4))) float facc_t;    // 4 fp32 acc
typedef __attribute__((ext_vector_type(4))) unsigned int u32x4;
typedef __attribute__((ext_vector_type(4))) unsigned short u16x4;

__device__ __forceinline__ float sigmoidf_(float v) { return 1.f / (1.f + __expf(-v)); }

__device__ __forceinline__ unsigned short f2bf(float f) {
    union { float f; unsigned u; } v; v.f = f;
    unsigned r = v.u + 0x7FFFu + ((v.u >> 16) & 1u);   // round-to-nearest-even
    return (unsigned short)(r >> 16);
}
__device__ __forceinline__ float bf2f(unsigned short u) {
    union { unsigned u; float f; } v; v.u = ((unsigned)u) << 16; return v.f;
}
__device__ __forceinline__ unsigned long long pack4(float4 v) {
    return (unsigned long long)f2bf(v.x)
         | ((unsigned long long)f2bf(v.y) << 16)
         | ((unsigned long long)f2bf(v.z) << 32)
         | ((unsigned long long)f2bf(v.w) << 48);
}

// 16B/lane global->LDS DMA. LDS base is wave-uniform; lane L lands at l + L*16B.
__device__ __forceinline__ void stage16(const unsigned short* g, unsigned short* l, int lane) {
#if __has_builtin(__builtin_amdgcn_global_load_lds)
    __builtin_amdgcn_global_load_lds(
        (const __attribute__((address_space(1))) void*)g,
        (__attribute__((address_space(3))) void*)l, 16, 0, 0);
#else
    *(u32x4*)(l + lane * 8) = *(const u32x4*)g;
#endif
}

struct CastArgs {
    const float4* src[3];
    unsigned long long* dst[3];
};

// ---------------------------------------------------------------------------
// PREPROC mega-kernel (round-12 proven version: coalesced LDS-staged logits).
// ---------------------------------------------------------------------------
#define LG_BLOCKS   ((S / 16) * KSLICES)                    // 1024
#define CAST_BLOCKS (3 * (HS * CDIM / 16 / 256))            // 1536
#define TGU_BLOCKS  (2 * E * (CDIM / 64) * (H / 64))        // 2048
#define TDN_BLOCKS  (E * (H / 64) * (CDIM / 64))            // 1024

__global__ __launch_bounds__(256) void preproc_kernel(
    const float* __restrict__ x, const float* __restrict__ rw,
    float* __restrict__ lgpart, unsigned short* __restrict__ xb,
    CastArgs ca,
    const float* __restrict__ gate_w, unsigned short* __restrict__ gwT,
    const float* __restrict__ up_w,  unsigned short* __restrict__ uwT,
    const float* __restrict__ down_w, unsigned short* __restrict__ dwT)
{
    __shared__ __align__(16) float sbuf[64 * 65];   // 16640 B, shared by partitions
    const int tid = threadIdx.x;
    int id = blockIdx.x;

    if (id < LG_BLOCKS) {
        // ---- logits + x cast, LDS-staged & coalesced ----
        const int ks = id >> 7;
        const int s0 = (id & 127) * 16;
        float* xs  = sbuf;              // [16][129] x-slab (pad +1: bank-safe)
        float* wsl = sbuf + 16 * 129;   // [16][129] rw-slab (total 16512 B)
#pragma unroll
        for (int r = 0; r < 2; ++r) {
            int idx = r * 256 + tid;          // 0..511
            int row = idx >> 5;               // 0..15
            int c4  = (idx & 31) * 4;         // 0..124
            float4 xv = *(const float4*)&x[(size_t)(s0 + row) * CDIM + ks * (CDIM / KSLICES) + c4];
            float4 wv = *(const float4*)&rw[(size_t)row * CDIM + ks * (CDIM / KSLICES) + c4];
            float* px = &xs[row * 129 + c4];
            px[0] = xv.x; px[1] = xv.y; px[2] = xv.z; px[3] = xv.w;
            float* pw = &wsl[row * 129 + c4];
            pw[0] = wv.x; pw[1] = wv.y; pw[2] = wv.z; pw[3] = wv.w;
        }
        __syncthreads();
        const int t = tid & 15, e = tid >> 4;
        const float* xr = &xs[t * 129];
        const float* wr = &wsl[e * 129];
        float acc = 0.f;
#pragma unroll 8
        for (int c = 0; c < CDIM / KSLICES / 4; ++c)
            acc += xr[c * 4 + 0] * wr[c * 4 + 0] + xr[c * 4 + 1] * wr[c * 4 + 1]
                 + xr[c * 4 + 2] * wr[c * 4 + 2] + xr[c * 4 + 3] * wr[c * 4 + 3];
        lgpart[((size_t)ks * S + s0 + t) * E + e] = acc;
        // coalesced cast: wave writes 4 x 256B contiguous segments
        const int tok = tid >> 4, off = (tid & 15) * 8;
        const float* pr = &xs[tok * 129 + off];
        float4 v0 = make_float4(pr[0], pr[1], pr[2], pr[3]);
        float4 v1 = make_float4(pr[4], pr[5], pr[6], pr[7]);
        unsigned long long* dst = (unsigned long long*)
            (xb + (size_t)(s0 + tok) * CDIM + ks * (CDIM / KSLICES) + off);
        dst[0] = pack4(v0);
        dst[1] = pack4(v1);
        return;
    }
    id -= LG_BLOCKS;

    if (id < CAST_BLOCKS) {
        // ---- shared-weight casts: 512 blocks per buffer, 4 float4/thread ----
        const int buf = id >> 9;
        const int i0 = (id & 511) * 1024 + tid;
        const float4* src = ca.src[buf];
        unsigned long long* dst = ca.dst[buf];
#pragma unroll
        for (int j = 0; j < 4; ++j)
            dst[i0 + j * 256] = pack4(src[i0 + j * 256]);
        return;
    }
    id -= CAST_BLOCKS;

    // ---- 64x64 vectorized transposes (round-5 version) ----
    float* tbuf = sbuf;   // [64][65]
    const float* src; unsigned short* dst; int R, Cc, zz, c0, r0;
    if (id < TGU_BLOCKS) {
        const int bx = id & 3; const int by = (id >> 2) & 15; const int bz = id >> 6;
        R = CDIM; Cc = H;
        src = (bz < E) ? gate_w : up_w;
        dst = (bz < E) ? gwT : uwT;
        zz = (bz < E) ? bz : bz - E;
        c0 = bx * 64; r0 = by * 64;
    } else {
        id -= TGU_BLOCKS;
        const int bx = id & 15; const int by = (id >> 4) & 3; const int bz = id >> 6;
        R = H; Cc = CDIM;
        src = down_w; dst = dwT; zz = bz;
        c0 = bx * 64; r0 = by * 64;
    }
    const size_t mo = (size_t)zz * R * Cc;
    src += mo; dst += mo;
    const int tx = tid & 15, ty = tid >> 4;   // 16 x 16
#pragma unroll
    for (int i = 0; i < 4; ++i) {
        const int row = ty + 16 * i;
        float4 v = *(const float4*)&src[(size_t)(r0 + row) * Cc + c0 + tx * 4];
        float* p = &tbuf[row * 65 + tx * 4];
        p[0] = v.x; p[1] = v.y; p[2] = v.z; p[3] = v.w;
    }
    __syncthreads();
#pragma unroll
    for (int j = 0; j < 4; ++j) {
        const int c = ty + 16 * j;
        u16x4 o;
#pragma unroll
        for (int i = 0; i < 4; ++i)
            o[i] = f2bf(tbuf[(tx * 4 + i) * 65 + c]);
        *(u16x4*)&dst[(size_t)(c0 + c) * R + r0 + tx * 4] = o;
    }
}

// ---------------------------------------------------------------------------
// K1b: route (hierarchical compaction, unchanged).
// ---------------------------------------------------------------------------
__global__ __launch_bounds__(256) void route_kernel(
    const float* __restrict__ lgpart, const float* __restrict__ bias,
    int* __restrict__ counts, int* __restrict__ list, float* __restrict__ wlist)
{
    __shared__ int lcount[E];
    __shared__ int lbase[E];
    const int tid = threadIdx.x;
    const int s = blockIdx.x * 256 + tid;
    if (tid < E) lcount[tid] = 0;
    float lgv[E];
#pragma unroll
    for (int i = 0; i < E; ++i) lgv[i] = 0.f;
#pragma unroll
    for (int ks = 0; ks < KSLICES; ++ks) {
        const float4* p = (const float4*)(lgpart + ((size_t)ks * S + s) * E);
#pragma unroll
        for (int q = 0; q < 4; ++q) {
            float4 v = p[q];
            lgv[q * 4 + 0] += v.x; lgv[q * 4 + 1] += v.y;
            lgv[q * 4 + 2] += v.z; lgv[q * 4 + 3] += v.w;
        }
    }
    float sc[E], sb[E];
#pragma unroll
    for (int e2 = 0; e2 < E; ++e2) {
        sc[e2] = 1.f / (1.f + __expf(-lgv[e2]));
        sb[e2] = sc[e2] + bias[e2];
    }
    float gsc[GNUM];
#pragma unroll
    for (int g = 0; g < GNUM; ++g) {
        int b_ = g * EPG;
        int m1 = 0; float v1 = sb[b_];
#pragma unroll
        for (int j = 1; j < EPG; ++j) if (sb[b_ + j] > v1) { v1 = sb[b_ + j]; m1 = j; }
        float v2 = -1e30f;
#pragma unroll
        for (int j = 0; j < EPG; ++j) if (j != m1 && sb[b_ + j] > v2) v2 = sb[b_ + j];
        gsc[g] = v1 + v2;
    }
    int g1 = 0;
#pragma unroll
    for (int g = 1; g < GNUM; ++g) if (gsc[g] > gsc[g1]) g1 = g;
    int g2 = (g1 == 0) ? 1 : 0;
#pragma unroll
    for (int g = 0; g < GNUM; ++g) if (g != g1 && gsc[g] > gsc[g2]) g2 = g;
    bool allowed[E];
#pragma unroll
    for (int e2 = 0; e2 < E; ++e2) {
        int g = e2 >> 2;
        allowed[e2] = (g == g1) || (g == g2);
    }
    int idx[TOPK]; float wk[TOPK];
#pragma unroll
    for (int k = 0; k < TOPK; ++k) {
        int best = 0; float bv = -1e30f;
#pragma unroll
        for (int e2 = 0; e2 < E; ++e2)
            if (allowed[e2] && sb[e2] > bv) { bv = sb[e2]; best = e2; }
        allowed[best] = false;
        idx[k] = best;
        wk[k] = sc[best];
    }
    float inv = 1.f / (wk[0] + wk[1] + wk[2] + wk[3] + 1e-20f);
    __syncthreads();
    int lpos[TOPK];
#pragma unroll
    for (int k = 0; k < TOPK; ++k)
        lpos[k] = atomicAdd(&lcount[idx[k]], 1);
    __syncthreads();
    if (tid < E)
        lbase[tid] = atomicAdd(&counts[tid], lcount[tid]);
    __syncthreads();
#pragma unroll
    for (int k = 0; k < TOPK; ++k) {
        int ee = idx[k];
        int pos = lbase[ee] + lpos[k];
        list[ee * S + pos] = s | (k << 16);
        wlist[ee * S + pos] = wk[k] * inv;
    }
}

// ---------------------------------------------------------------------------
// m97-style MFMA GEMMs, single-buffer. K4 @ BM=128/BK=64 (proven),
// K6/K7 @ 64x64/BK=64 (proven), K5 NOW @ BK=128 (K=2048: drain events
// 32 -> 16; LDS 32 KB so occupancy unchanged — avoids m132's confound).
// ---------------------------------------------------------------------------

// K4: shared gate+up fused SwiGLU -> shb bf16 [S][HS]. BM=128/BN=64, BK=64.
// grid (HS/64=32, S/128=16).
__global__ __launch_bounds__(256) void gemm_shared_gateup(
    const unsigned short* __restrict__ xb, const unsigned short* __restrict__ gb,
    const unsigned short* __restrict__ ub, unsigned short* __restrict__ shb)
{
    __shared__ __align__(16) unsigned short As[2 * 128 * 32];
    __shared__ __align__(16) unsigned short Bg[2 * 64 * 32];
    __shared__ __align__(16) unsigned short Bu[2 * 64 * 32];
    const int tid = threadIdx.x;
    const int lane = tid & 63, w = tid >> 6;
    const int l15 = lane & 15, q = lane >> 4;
    const int r0 = blockIdx.y * 128;
    const int c0 = blockIdx.x * 64;
    const int wr = (w >> 1) * 64, wc = (w & 1) * 32;
    const int Lrow = lane >> 2;
    const int gseg = (lane & 3) ^ ((lane >> 3) & 3);
    const unsigned short* gA1 = xb + (size_t)(r0 + w * 16 + Lrow) * CDIM + gseg * 8;
    const unsigned short* gA2 = gA1 + (size_t)64 * CDIM;
    const unsigned short* gG  = gb + (size_t)(c0 + w * 16 + Lrow) * CDIM + gseg * 8;
    const unsigned short* gU  = ub + (size_t)(c0 + w * 16 + Lrow) * CDIM + gseg * 8;
    unsigned short* lA1 = &As[(w * 16) * 32];
    unsigned short* lA2 = lA1 + 64 * 32;
    unsigned short* lG  = &Bg[(w * 16) * 32];
    unsigned short* lU  = &Bu[(w * 16) * 32];
    const int swq = (q ^ ((l15 >> 1) & 3)) * 8;
    facc_t accg[4][2], accu[4][2];
#pragma unroll
    for (int i = 0; i < 4; ++i)
#pragma unroll
        for (int j = 0; j < 2; ++j) { accg[i][j] = 0.f; accu[i][j] = 0.f; }
    for (int k0 = 0; k0 < CDIM; k0 += 64) {
        stage16(gA1 + k0,      lA1,             lane);
        stage16(gA1 + k0 + 32, lA1 + 128 * 32,  lane);
        stage16(gA2 + k0,      lA2,             lane);
        stage16(gA2 + k0 + 32, lA2 + 128 * 32,  lane);
        stage16(gG + k0,       lG,              lane);
        stage16(gG + k0 + 32,  lG + 64 * 32,    lane);
        stage16(gU + k0,       lU,              lane);
        stage16(gU + k0 + 32,  lU + 64 * 32,    lane);
        __syncthreads();
#pragma unroll
        for (int kk = 0; kk < 2; ++kk) {
            const unsigned short* Ah = &As[kk * 128 * 32];
            const unsigned short* Gh = &Bg[kk * 64 * 32];
            const unsigned short* Uh = &Bu[kk * 64 * 32];
            bfrag_t af[4], gf[2], uf[2];
#pragma unroll
            for (int i = 0; i < 4; ++i)
                af[i] = *(const bfrag_t*)&Ah[(wr + i * 16 + l15) * 32 + swq];
#pragma unroll
            for (int j = 0; j < 2; ++j) {
                gf[j] = *(const bfrag_t*)&Gh[(wc + j * 16 + l15) * 32 + swq];
                uf[j] = *(const bfrag_t*)&Uh[(wc + j * 16 + l15) * 32 + swq];
            }
#pragma unroll
            for (int i = 0; i < 4; ++i)
#pragma unroll
                for (int j = 0; j < 2; ++j) {
                    accg[i][j] = __builtin_amdgcn_mfma_f32_16x16x32_bf16(af[i], gf[j], accg[i][j], 0, 0, 0);
                    accu[i][j] = __builtin_amdgcn_mfma_f32_16x16x32_bf16(af[i], uf[j], accu[i][j], 0, 0, 0);
                }
        }
        __syncthreads();
    }
#pragma unroll
    for (int i = 0; i < 4; ++i)
#pragma unroll
        for (int j = 0; j < 2; ++j)
#pragma unroll
            for (int r = 0; r < 4; ++r) {
                int row = r0 + wr + i * 16 + q * 4 + r;
                int col = c0 + wc + j * 16 + l15;
                float g = accg[i][j][r], u = accu[i][j][r];
                shb[(size_t)row * HS + col] = f2bf(g * sigmoidf_(g) * u);
            }
}

// K5: shared down-proj + routed-sum epilogue -> out fp32 [S][CDIM].
// BM=64/BN=64, BK=128 (four 32-wide halves), K=HS. grid (CDIM/64=16, S/64=32).
// LDS 32 KB -> occupancy unchanged; barrier-drain events 32 -> 16. RUNS LAST.
__global__ __launch_bounds__(256) void gemm_shared_down(
    const unsigned short* __restrict__ shb, const unsigned short* __restrict__ db,
    const unsigned short* __restrict__ dbuf, float* __restrict__ out)
{
    __shared__ __align__(16) unsigned short As[4 * 64 * 32];
    __shared__ __align__(16) unsigned short Bs[4 * 64 * 32];
    const int tid = threadIdx.x;
    const int lane = tid & 63, w = tid >> 6;
    const int l15 = lane & 15, q = lane >> 4;
    const int r0 = blockIdx.y * 64;
    const int c0 = blockIdx.x * 64;
    const int wr = (w >> 1) * 32, wc = (w & 1) * 32;
    const int Lrow = lane >> 2;
    const int gseg = (lane & 3) ^ ((lane >> 3) & 3);
    const unsigned short* gA = shb + (size_t)(r0 + w * 16 + Lrow) * HS + gseg * 8;
    const unsigned short* gB = db + (size_t)(c0 + w * 16 + Lrow) * HS + gseg * 8;
    unsigned short* lA = &As[(w * 16) * 32];
    unsigned short* lB = &Bs[(w * 16) * 32];
    const int swq = (q ^ ((l15 >> 1) & 3)) * 8;
    facc_t acc[2][2];
#pragma unroll
    for (int i = 0; i < 2; ++i)
#pragma unroll
        for (int j = 0; j < 2; ++j) acc[i][j] = 0.f;
    for (int k0 = 0; k0 < HS; k0 += 128) {
#pragma unroll
        for (int h = 0; h < 4; ++h) {
            stage16(gA + k0 + h * 32, lA + h * 64 * 32, lane);
            stage16(gB + k0 + h * 32, lB + h * 64 * 32, lane);
        }
        __syncthreads();
#pragma unroll
        for (int kk = 0; kk < 4; ++kk) {
            const unsigned short* Ah = &As[kk * 64 * 32];
            const unsigned short* Bh = &Bs[kk * 64 * 32];
            bfrag_t af[2], bf[2];
#pragma unroll
            for (int i = 0; i < 2; ++i) af[i] = *(const bfrag_t*)&Ah[(wr + i * 16 + l15) * 32 + swq];
#pragma unroll
            for (int j = 0; j < 2; ++j) bf[j] = *(const bfrag_t*)&Bh[(wc + j * 16 + l15) * 32 + swq];
#pragma unroll
            for (int i = 0; i < 2; ++i)
#pragma unroll
                for (int j = 0; j < 2; ++j)
                    acc[i][j] = __builtin_amdgcn_mfma_f32_16x16x32_bf16(af[i], bf[j], acc[i][j], 0, 0, 0);
        }
        __syncthreads();
    }
#pragma unroll
    for (int i = 0; i < 2; ++i)
#pragma unroll
        for (int j = 0; j < 2; ++j)
#pragma unroll
            for (int r = 0; r < 4; ++r) {
                int row = r0 + wr + i * 16 + q * 4 + r;
                int col = c0 + wc + j * 16 + l15;
                float v = acc[i][j][r];
                const unsigned short* dp = dbuf + ((size_t)row * TOPK) * CDIM + col;
#pragma unroll
                for (int k = 0; k < TOPK; ++k) v += bf2f(dp[(size_t)k * CDIM]);
                out[(size_t)row * CDIM + col] = v;
            }
}

// K6: routed gate+up, gathered A rows, weighted SwiGLU -> hbuf bf16 [S*4][H].
// BM=64/BN=64, BK=64. grid (E, H/64=4, S/64=32).
__global__ __launch_bounds__(256) void gemm_routed_gateup(
    const unsigned short* __restrict__ xb, const unsigned short* __restrict__ gwT,
    const unsigned short* __restrict__ uwT, const int* __restrict__ counts,
    const int* __restrict__ list, const float* __restrict__ wlist,
    unsigned short* __restrict__ hbuf)
{
    const int e = blockIdx.x;
    const int n = counts[e];
    const int t0 = blockIdx.z * 64;
    if (t0 >= n) return;
    const int h0 = blockIdx.y * 64;
    __shared__ int toks[64];
    __shared__ int hrw[64];
    __shared__ float wv[64];
    __shared__ __align__(16) unsigned short As[2 * 64 * 32];
    __shared__ __align__(16) unsigned short Bg[2 * 64 * 32];
    __shared__ __align__(16) unsigned short Bu[2 * 64 * 32];
    const int tid = threadIdx.x;
    if (tid < 64) {
        int p = t0 + tid;
        if (p < n) {
            int pk = list[e * S + p];
            toks[tid] = pk & 0xFFFF;
            hrw[tid] = (pk & 0xFFFF) * TOPK + (pk >> 16);
            wv[tid] = wlist[e * S + p];
        } else { toks[tid] = 0; hrw[tid] = 0; wv[tid] = 0.f; }
    }
    __syncthreads();
    const int lane = tid & 63, w = tid >> 6;
    const int l15 = lane & 15, q = lane >> 4;
    const int wr = (w >> 1) * 32, wc = (w & 1) * 32;
    const int Lrow = lane >> 2;
    const int gseg = (lane & 3) ^ ((lane >> 3) & 3);
    const int tokA = toks[w * 16 + Lrow];        // per-lane gathered A row
    const unsigned short* gA = xb + (size_t)tokA * CDIM + gseg * 8;
    const unsigned short* gG = gwT + ((size_t)e * H + h0 + w * 16 + Lrow) * CDIM + gseg * 8;
    const unsigned short* gU = uwT + ((size_t)e * H + h0 + w * 16 + Lrow) * CDIM + gseg * 8;
    unsigned short* lA = &As[(w * 16) * 32];
    unsigned short* lG = &Bg[(w * 16) * 32];
    unsigned short* lU = &Bu[(w * 16) * 32];
    const int swq = (q ^ ((l15 >> 1) & 3)) * 8;
    facc_t accg[2][2], accu[2][2];
#pragma unroll
    for (int i = 0; i < 2; ++i)
#pragma unroll
        for (int j = 0; j < 2; ++j) { accg[i][j] = 0.f; accu[i][j] = 0.f; }
    for (int k0 = 0; k0 < CDIM; k0 += 64) {
        stage16(gA + k0,      lA,            lane);
        stage16(gA + k0 + 32, lA + 64 * 32,  lane);
        stage16(gG + k0,      lG,            lane);
        stage16(gG + k0 + 32, lG + 64 * 32,  lane);
        stage16(gU + k0,      lU,            lane);
        stage16(gU + k0 + 32, lU + 64 * 32,  lane);
        __syncthreads();
#pragma unroll
        for (int kk = 0; kk < 2; ++kk) {
            const unsigned short* Ah = &As[kk * 64 * 32];
            const unsigned short* Gh = &Bg[kk * 64 * 32];
            const unsigned short* Uh = &Bu[kk * 64 * 32];
            bfrag_t af[2], gf[2], uf[2];
#pragma unroll
            for (int i = 0; i < 2; ++i) af[i] = *(const bfrag_t*)&Ah[(wr + i * 16 + l15) * 32 + swq];
#pragma unroll
            for (int j = 0; j < 2; ++j) {
                gf[j] = *(const bfrag_t*)&Gh[(wc + j * 16 + l15) * 32 + swq];
                uf[j] = *(const bfrag_t*)&Uh[(wc + j * 16 + l15) * 32 + swq];
            }
#pragma unroll
            for (int i = 0; i < 2; ++i)
#pragma unroll
                for (int j = 0; j < 2; ++j) {
                    accg[i][j] = __builtin_amdgcn_mfma_f32_16x16x32_bf16(af[i], gf[j], accg[i][j], 0, 0, 0);
                    accu[i][j] = __builtin_amdgcn_mfma_f32_16x16x32_bf16(af[i], uf[j], accu[i][j], 0, 0, 0);
                }
        }
        __syncthreads();
    }
#pragma unroll
    for (int i = 0; i < 2; ++i)
#pragma unroll
        for (int j = 0; j < 2; ++j)
#pragma unroll
            for (int r = 0; r < 4; ++r) {
                int li = wr + i * 16 + q * 4 + r;
                if (t0 + li < n) {
                    int col = h0 + wc + j * 16 + l15;
                    float g = accg[i][j][r], u = accu[i][j][r];
                    hbuf[(size_t)hrw[li] * H + col] = f2bf(wv[li] * g * sigmoidf_(g) * u);
                }
            }
}

// K7: routed down-proj -> dbuf bf16 [S*4][CDIM]. BM=64/BN=64, BK=64, K=H=256.
// grid (E, CDIM/64=16, S/64=32).
__global__ __launch_bounds__(256) void gemm_routed_down(
    const unsigned short* __restrict__ hbuf, const unsigned short* __restrict__ dwT,
    const int* __restrict__ counts, const int* __restrict__ list,
    unsigned short* __restrict__ dbuf)
{
    const int e = blockIdx.x;
    const int n = counts[e];
    const int t0 = blockIdx.z * 64;
    if (t0 >= n) return;
    const int c0 = blockIdx.y * 64;
    __shared__ int hrw[64];
    __shared__ __align__(16) unsigned short As[2 * 64 * 32];
    __shared__ __align__(16) unsigned short Bs[2 * 64 * 32];
    const int tid = threadIdx.x;
    if (tid < 64) {
        int p = t0 + tid;
        int pk = (p < n) ? list[e * S + p] : 0;
        hrw[tid] = (pk & 0xFFFF) * TOPK + (pk >> 16);
    }
    __syncthreads();
    const int lane = tid & 63, w = tid >> 6;
    const int l15 = lane & 15, q = lane >> 4;
    const int wr = (w >> 1) * 32, wc = (w & 1) * 32;
    const int Lrow = lane >> 2;
    const int gseg = (lane & 3) ^ ((lane >> 3) & 3);
    const int arow = hrw[w * 16 + Lrow];
    const unsigned short* gA = hbuf + (size_t)arow * H + gseg * 8;
    const unsigned short* gB = dwT + ((size_t)e * CDIM + c0 + w * 16 + Lrow) * H + gseg * 8;
    unsigned short* lA = &As[(w * 16) * 32];
    unsigned short* lB = &Bs[(w * 16) * 32];
    const int swq = (q ^ ((l15 >> 1) & 3)) * 8;
    facc_t acc[2][2];
#pragma unroll
    for (int i = 0; i < 2; ++i)
#pragma unroll
        for (int j = 0; j < 2; ++j) acc[i][j] = 0.f;
    for (int k0 = 0; k0 < H; k0 += 64) {
        stage16(gA + k0,      lA,            lane);
        stage16(gA + k0 + 32, lA + 64 * 32,  lane);
        stage16(gB + k0,      lB,            lane);
        stage16(gB + k0 + 32, lB + 64 * 32,  lane);
        __syncthreads();
#pragma unroll
        for (int kk = 0; kk < 2; ++kk) {
            const unsigned short* Ah = &As[kk * 64 * 32];
            const unsigned short* Bh = &Bs[kk * 64 * 32];
            bfrag_t af[2], bf[2];
#pragma unroll
            for (int i = 0; i < 2; ++i) af[i] = *(const bfrag_t*)&Ah[(wr + i * 16 + l15) * 32 + swq];
#pragma unroll
            for (int j = 0; j < 2; ++j) bf[j] = *(const bfrag_t*)&Bh[(wc + j * 16 + l15) * 32 + swq];
#pragma unroll
            for (int i = 0; i < 2; ++i)
#pragma unroll
                for (int j = 0; j < 2; ++j)
                    acc[i][j] = __builtin_amdgcn_mfma_f32_16x16x32_bf16(af[i], bf[j], acc[i][j], 0, 0, 0);
        }
        __syncthreads();
    }
#pragma unroll
    for (int i = 0; i < 2; ++i)
#pragma unroll
        for (int j = 0; j < 2; ++j)
#pragma unroll
            for (int r = 0; r < 4; ++r) {
                int li = wr + i * 16 + q * 4 + r;
                if (t0 + li < n) {
                    int col = c0 + wc + j * 16 + l15;
                    dbuf[(size_t)hrw[li] * CDIM + col] = f2bf(acc[i][j][r]);
                }
            }
}

// ---------------------------------------------------------------------------
extern "C" void kernel_launch(void* const* d_in, const int* in_sizes, int n_in,
                              void* d_out, int out_size, void* d_ws, size_t ws_size,
                              hipStream_t stream)
{
    const float* x        = (const float*)d_in[0];
    const float* router_w = (const float*)d_in[1];
    const float* bias     = (const float*)d_in[2];
    const float* gate_w   = (const float*)d_in[3];
    const float* up_w     = (const float*)d_in[4];
    const float* down_w   = (const float*)d_in[5];
    const float* sgw      = (const float*)d_in[6];
    const float* suw      = (const float*)d_in[7];
    const float* sdw      = (const float*)d_in[8];
    float* out = (float*)d_out;

    char* ws = (char*)d_ws;
    size_t off = 0;
    int* counts = (int*)(ws + off);            off += 256;
    int* list   = (int*)(ws + off);            off += (size_t)E * S * 4;
    float* wlist = (float*)(ws + off);         off += (size_t)E * S * 4;
    unsigned short* xb  = (unsigned short*)(ws + off); off += (size_t)S * CDIM * 2;
    unsigned short* sgb = (unsigned short*)(ws + off); off += (size_t)HS * CDIM * 2;
    unsigned short* sub = (unsigned short*)(ws + off); off += (size_t)HS * CDIM * 2;
    unsigned short* sdb = (unsigned short*)(ws + off); off += (size_t)CDIM * HS * 2;
    unsigned short* gwT = (unsigned short*)(ws + off); off += (size_t)E * H * CDIM * 2;
    unsigned short* uwT = (unsigned short*)(ws + off); off += (size_t)E * H * CDIM * 2;
    unsigned short* dwT = (unsigned short*)(ws + off); off += (size_t)E * CDIM * H * 2;
    unsigned short* shb = (unsigned short*)(ws + off); off += (size_t)S * HS * 2;
    unsigned short* hbuf = (unsigned short*)(ws + off); off += (size_t)S * TOPK * H * 2;
    unsigned short* dbuf = (unsigned short*)(ws + off); off += (size_t)S * TOPK * CDIM * 2;
    // lgpart (8*S*E floats = 1 MiB) aliases dbuf (consumed by route_kernel
    // before gemm_routed_down writes dbuf; same stream, serial).
    float* lgpart = (float*)dbuf;

    hipMemsetAsync(counts, 0, E * sizeof(int), stream);

    CastArgs ca;
    ca.src[0] = (const float4*)sgw; ca.dst[0] = (unsigned long long*)sgb;
    ca.src[1] = (const float4*)suw; ca.dst[1] = (unsigned long long*)sub;
    ca.src[2] = (const float4*)sdw; ca.dst[2] = (unsigned long long*)sdb;

    preproc_kernel<<<LG_BLOCKS + CAST_BLOCKS + TGU_BLOCKS + TDN_BLOCKS, 256, 0, stream>>>(
        x, router_w, lgpart, xb, ca, gate_w, gwT, up_w, uwT, down_w, dwT);

    route_kernel<<<S / 256, 256, 0, stream>>>(lgpart, bias, counts, list, wlist);

    gemm_shared_gateup<<<dim3(HS / 64, S / 128), 256, 0, stream>>>(xb, sgb, sub, shb);
    gemm_routed_gateup<<<dim3(E, H / 64, S / 64), 256, 0, stream>>>(xb, gwT, uwT, counts, list, wlist, hbuf);
    gemm_routed_down<<<dim3(E, CDIM / 64, S / 64), 256, 0, stream>>>(hbuf, dwT, counts, list, dbuf);
    // LAST: shared down-proj with fused routed-sum epilogue (reads dbuf).
    gemm_shared_down<<<dim3(CDIM / 64, S / 64), 256, 0, stream>>>(shb, sdb, dbuf, out);
}